// Round 1
// baseline (37272.900 us; speedup 1.0000x reference)
//
#include <hip/hip_runtime.h>
#include <math.h>

#define N_LAYERS 12
#define D_MODEL 768
#define N_HEAD 12
#define HD 64
#define T_SEQ 1024
#define BATCH 2
#define M_ROWS (BATCH*T_SEQ)   // 2048
#define V_VOCAB 50257
#define R_LORA 16
#define LORA_SCALE 2.0f
#define LN_EPS 1e-5f

// ---------- ordered-uint float key helpers (for min/max atomics) ----------
__device__ __forceinline__ unsigned fkey(float f){
  unsigned u = __float_as_uint(f);
  return (u & 0x80000000u) ? ~u : (u | 0x80000000u);
}
__device__ __forceinline__ float funkey(unsigned k){
  unsigned u = (k & 0x80000000u) ? (k & 0x7fffffffu) : ~k;
  return __uint_as_float(u);
}

// ---------- scratch init ----------
__global__ void init_scratch(unsigned* wabs, unsigned* kvkeys){
  int i = threadIdx.x;
  if (i < 48){
    wabs[i] = 0u;                                  // absmax >= 0, int-compare ok
    int t = i & 3;                                 // kmin,kmax,vmin,vmax
    kvkeys[i] = (t==0 || t==2) ? 0xFFFFFFFFu : 0u; // min-slots=+inf-key, max-slots=-inf-key
  }
}

// ---------- embedding ----------
__global__ __launch_bounds__(256) void embed_kernel(const int* __restrict__ ids,
    const float* __restrict__ wte, const float* __restrict__ wpe, float* __restrict__ h){
  int m = blockIdx.x;
  int t = m & (T_SEQ-1);
  int id = ids[m];
  const float* wr = wte + (size_t)id * D_MODEL;
  const float* pr = wpe + (size_t)t  * D_MODEL;
  float* hr = h + (size_t)m * D_MODEL;
  #pragma unroll
  for (int i=0;i<3;i++){ int d = threadIdx.x + i*256; hr[d] = wr[d] + pr[d]; }
}

// ---------- per-tensor weight absmax (48 tensors) ----------
__global__ __launch_bounds__(256) void wabs_reduce(const float* __restrict__ qkv_w,
    const float* __restrict__ ao_w, const float* __restrict__ fc_w,
    const float* __restrict__ mo_w, unsigned* wabs){
  int t = blockIdx.y; int layer = t >> 2; int ty = t & 3;
  const float* base; size_t n;
  if (ty==0){ base = qkv_w + (size_t)layer*D_MODEL*3*D_MODEL; n = (size_t)D_MODEL*3*D_MODEL; }
  else if (ty==1){ base = ao_w + (size_t)layer*D_MODEL*D_MODEL; n = (size_t)D_MODEL*D_MODEL; }
  else if (ty==2){ base = fc_w + (size_t)layer*D_MODEL*4*D_MODEL; n = (size_t)D_MODEL*4*D_MODEL; }
  else { base = mo_w + (size_t)layer*4*D_MODEL*D_MODEL; n = (size_t)4*D_MODEL*D_MODEL; }
  float mx = 0.0f;
  for (size_t i = (size_t)blockIdx.x*256 + threadIdx.x; i < n; i += (size_t)gridDim.x*256)
    mx = fmaxf(mx, fabsf(base[i]));
  for (int o=32;o>0;o>>=1) mx = fmaxf(mx, __shfl_down(mx, o));
  if ((threadIdx.x & 63) == 0) atomicMax((int*)&wabs[t], __float_as_int(mx));
}

// ---------- layernorm (row per block) ----------
__global__ __launch_bounds__(256) void ln_kernel(const float* __restrict__ in, float* __restrict__ out,
    const float* __restrict__ g, const float* __restrict__ b){
  int m = blockIdx.x;
  const float* row = in + (size_t)m*D_MODEL;
  int t = threadIdx.x;
  float xv[3];
  #pragma unroll
  for (int i=0;i<3;i++) xv[i] = row[t + i*256];
  __shared__ float red[4];
  float s = xv[0]+xv[1]+xv[2];
  for (int o=32;o>0;o>>=1) s += __shfl_down(s, o);
  if ((t&63)==0) red[t>>6] = s;
  __syncthreads();
  float mean = (red[0]+red[1]+red[2]+red[3]) / 768.0f;
  __syncthreads();
  float d0 = xv[0]-mean, d1 = xv[1]-mean, d2 = xv[2]-mean;
  float sq = d0*d0 + d1*d1 + d2*d2;
  for (int o=32;o>0;o>>=1) sq += __shfl_down(sq, o);
  if ((t&63)==0) red[t>>6] = sq;
  __syncthreads();
  float var = (red[0]+red[1]+red[2]+red[3]) / 768.0f;
  float inv = 1.0f / sqrtf(var + LN_EPS);
  float* orow = out + (size_t)m*D_MODEL;
  #pragma unroll
  for (int i=0;i<3;i++){ int d = t + i*256; orow[d] = (xv[i]-mean)*inv*g[d] + b[d]; }
}

// ---------- LoRA xa = X @ A  [M,K]@[K,16] ----------
__global__ __launch_bounds__(256) void lora_xa_kernel(const float* __restrict__ X,
    const float* __restrict__ A, float* __restrict__ xa, int K){
  int m = blockIdx.x*16 + (threadIdx.x >> 4);
  int r = threadIdx.x & 15;
  const float* xr = X + (size_t)m*K;
  float a0=0.f,a1=0.f,a2=0.f,a3=0.f;
  for (int k=0;k<K;k+=4){
    a0 += xr[k  ] * A[(size_t)(k  )*R_LORA + r];
    a1 += xr[k+1] * A[(size_t)(k+1)*R_LORA + r];
    a2 += xr[k+2] * A[(size_t)(k+2)*R_LORA + r];
    a3 += xr[k+3] * A[(size_t)(k+3)*R_LORA + r];
  }
  xa[(size_t)m*R_LORA + r] = (a0+a1)+(a2+a3);
}

// ---------- main QLoRA GEMM: out = [resid +] X @ fq_sym(W) + bias + (xa@Bl)*2 [, gelu] ----------
template<bool RESID, bool GELU>
__global__ __launch_bounds__(256) void gemm_qlora(const float* __restrict__ Xp,
    const float* __restrict__ Wp, const unsigned* __restrict__ wabs_slot,
    const float* __restrict__ bias, const float* __restrict__ xa,
    const float* __restrict__ Bl, const float* resid, float* out, int N, int K){
  __shared__ float As[16][68];
  __shared__ float Bs[16][68];
  int m0 = blockIdx.x*64, n0 = blockIdx.y*64;
  int tid = threadIdx.x, tx = tid & 15, ty = tid >> 4;
  float s = fmaxf(__uint_as_float(wabs_slot[0]) / 127.0f, 1e-8f);
  float acc[4][4] = {};
  for (int k0=0;k0<K;k0+=16){
    #pragma unroll
    for (int i=0;i<4;i++){
      int e = tid + i*256;
      int r = e >> 4, c = e & 15;
      As[c][r] = Xp[(size_t)(m0+r)*K + k0 + c];
      int rb = e >> 6, cb = e & 63;
      float w = Wp[(size_t)(k0+rb)*N + n0 + cb];
      float q = rintf(w / s);
      Bs[rb][cb] = fminf(fmaxf(q, -128.0f), 127.0f) * s;
    }
    __syncthreads();
    #pragma unroll
    for (int kk=0;kk<16;kk++){
      float av[4], bv[4];
      #pragma unroll
      for (int i=0;i<4;i++) av[i] = As[kk][i*16+ty];
      #pragma unroll
      for (int j=0;j<4;j++) bv[j] = Bs[kk][j*16+tx];
      #pragma unroll
      for (int i=0;i<4;i++)
        #pragma unroll
        for (int j=0;j<4;j++) acc[i][j] += av[i]*bv[j];
    }
    __syncthreads();
  }
  #pragma unroll
  for (int i=0;i<4;i++){
    int m = m0 + i*16 + ty;
    float xr[R_LORA];
    #pragma unroll
    for (int r=0;r<R_LORA;r++) xr[r] = xa[(size_t)m*R_LORA + r];
    #pragma unroll
    for (int j=0;j<4;j++){
      int n = n0 + j*16 + tx;
      float v = acc[i][j] + bias[n];
      float lo = 0.f;
      #pragma unroll
      for (int r=0;r<R_LORA;r++) lo += xr[r] * Bl[(size_t)r*N + n];
      v += LORA_SCALE * lo;
      if (RESID) v += resid[(size_t)m*N + n];
      if (GELU)  v = 0.5f*v*(1.0f + erff(v*0.70710678118654752f));
      out[(size_t)m*N + n] = v;
    }
  }
}

// ---------- k/v per-tensor min/max ----------
__global__ __launch_bounds__(256) void kv_minmax(const float* __restrict__ qkv, unsigned* keys){
  float kmn=1e30f, kmx=-1e30f, vmn=1e30f, vmx=-1e30f;
  const size_t n = (size_t)M_ROWS * D_MODEL;
  for (size_t i = (size_t)blockIdx.x*256 + threadIdx.x; i < n; i += (size_t)gridDim.x*256){
    size_t m = i / D_MODEL, c = i % D_MODEL;
    float kv = qkv[m*(3*D_MODEL) + D_MODEL   + c];
    float vv = qkv[m*(3*D_MODEL) + 2*D_MODEL + c];
    kmn = fminf(kmn, kv); kmx = fmaxf(kmx, kv);
    vmn = fminf(vmn, vv); vmx = fmaxf(vmx, vv);
  }
  for (int o=32;o>0;o>>=1){
    kmn = fminf(kmn, __shfl_down(kmn,o));
    kmx = fmaxf(kmx, __shfl_down(kmx,o));
    vmn = fminf(vmn, __shfl_down(vmn,o));
    vmx = fmaxf(vmx, __shfl_down(vmx,o));
  }
  if ((threadIdx.x & 63) == 0){
    atomicMin(&keys[0], fkey(kmn));
    atomicMax(&keys[1], fkey(kmx));
    atomicMin(&keys[2], fkey(vmn));
    atomicMax(&keys[3], fkey(vmx));
  }
}

// ---------- apply asymmetric fake-quant to k and v in place ----------
__global__ __launch_bounds__(256) void kv_apply(float* qkv, const unsigned* __restrict__ keys){
  float kmn = funkey(keys[0]), kmx = funkey(keys[1]);
  float vmn = funkey(keys[2]), vmx = funkey(keys[3]);
  float ks = fmaxf((kmx - kmn) / 255.0f, 1e-8f);
  float kz = rintf(-kmn / ks);
  float vs = fmaxf((vmx - vmn) / 255.0f, 1e-8f);
  float vz = rintf(-vmn / vs);
  const size_t n = (size_t)M_ROWS * D_MODEL;
  for (size_t i = (size_t)blockIdx.x*256 + threadIdx.x; i < n; i += (size_t)gridDim.x*256){
    size_t m = i / D_MODEL, c = i % D_MODEL;
    float* kp = &qkv[m*(3*D_MODEL) + D_MODEL + c];
    float* vp = &qkv[m*(3*D_MODEL) + 2*D_MODEL + c];
    float xk = *kp;
    float qk = fminf(fmaxf(rintf(xk/ks) + kz, 0.0f), 255.0f);
    *kp = (qk - kz) * ks;
    float xv = *vp;
    float qv = fminf(fmaxf(rintf(xv/vs) + vz, 0.0f), 255.0f);
    *vp = (qv - vz) * vs;
  }
}

// ---------- causal attention, one wave per 64 q-rows, online softmax per thread ----------
__global__ __launch_bounds__(64) void attention_kernel(const float* __restrict__ qkv, float* __restrict__ att){
  int qt = blockIdx.x;           // 0..15
  int bh = blockIdx.y;           // 0..23
  int b = bh / N_HEAD, hh = bh % N_HEAD;
  int tid = threadIdx.x;
  int qi = qt*64 + tid;
  const float* base = qkv + (size_t)b * T_SEQ * (3*D_MODEL);
  float q[HD];
  #pragma unroll
  for (int d=0; d<HD; d++) q[d] = base[(size_t)qi*(3*D_MODEL) + hh*HD + d];
  float o[HD];
  #pragma unroll
  for (int d=0; d<HD; d++) o[d] = 0.0f;
  float mrun = -1e30f, lrun = 0.0f;
  __shared__ float Ks[64][HD];
  __shared__ float Vs[64][HD];
  for (int kt=0; kt<=qt; kt++){
    for (int r=0;r<64;r++){
      Ks[r][tid] = base[(size_t)(kt*64+r)*(3*D_MODEL) + D_MODEL   + hh*HD + tid];
      Vs[r][tid] = base[(size_t)(kt*64+r)*(3*D_MODEL) + 2*D_MODEL + hh*HD + tid];
    }
    __syncthreads();
    int kmax = min(64, qi - kt*64 + 1);
    for (int kk=0; kk<kmax; kk++){
      float s0=0.f,s1=0.f,s2=0.f,s3=0.f;
      #pragma unroll
      for (int d=0; d<HD; d+=4){
        s0 += q[d  ]*Ks[kk][d  ];
        s1 += q[d+1]*Ks[kk][d+1];
        s2 += q[d+2]*Ks[kk][d+2];
        s3 += q[d+3]*Ks[kk][d+3];
      }
      float s = ((s0+s1)+(s2+s3)) * 0.125f;
      float nm = fmaxf(mrun, s);
      float sc = expf(mrun - nm);
      float p  = expf(s - nm);
      lrun = lrun*sc + p;
      #pragma unroll
      for (int d=0; d<HD; d++) o[d] = o[d]*sc + p*Vs[kk][d];
      mrun = nm;
    }
    __syncthreads();
  }
  float rl = 1.0f / lrun;
  float* orow = att + (size_t)(b*T_SEQ + qi)*D_MODEL + hh*HD;
  #pragma unroll
  for (int d=0; d<HD; d++) orow[d] = o[d]*rl;
}

// ---------- lm_head: out = X @ wte^T ----------
__global__ __launch_bounds__(256) void gemm_lmhead(const float* __restrict__ X,
    const float* __restrict__ Wt, float* __restrict__ out){
  __shared__ float As[16][68];
  __shared__ float Bs[16][68];
  int m0 = blockIdx.x*64, n0 = blockIdx.y*64;
  int tid = threadIdx.x, tx = tid & 15, ty = tid >> 4;
  float acc[4][4] = {};
  for (int k0=0;k0<D_MODEL;k0+=16){
    #pragma unroll
    for (int i=0;i<4;i++){
      int e = tid + i*256;
      int r = e >> 4, c = e & 15;
      As[c][r] = X[(size_t)(m0+r)*D_MODEL + k0 + c];
      int n = n0 + r;
      Bs[c][r] = (n < V_VOCAB) ? Wt[(size_t)n*D_MODEL + k0 + c] : 0.0f;
    }
    __syncthreads();
    #pragma unroll
    for (int kk=0;kk<16;kk++){
      float av[4], bv[4];
      #pragma unroll
      for (int i=0;i<4;i++) av[i] = As[kk][i*16+ty];
      #pragma unroll
      for (int j=0;j<4;j++) bv[j] = Bs[kk][j*16+tx];
      #pragma unroll
      for (int i=0;i<4;i++)
        #pragma unroll
        for (int j=0;j<4;j++) acc[i][j] += av[i]*bv[j];
    }
    __syncthreads();
  }
  #pragma unroll
  for (int i=0;i<4;i++){
    int m = m0 + i*16 + ty;
    #pragma unroll
    for (int j=0;j<4;j++){
      int n = n0 + j*16 + tx;
      if (n < V_VOCAB) out[(size_t)m*V_VOCAB + n] = acc[i][j];
    }
  }
}

extern "C" void kernel_launch(void* const* d_in, const int* in_sizes, int n_in,
                              void* d_out, int out_size, void* d_ws, size_t ws_size,
                              hipStream_t stream){
  const int*   ids   = (const int*)  d_in[0];
  const float* wte   = (const float*)d_in[1];
  const float* wpe   = (const float*)d_in[2];
  const float* ln1_g = (const float*)d_in[3];
  const float* ln1_b = (const float*)d_in[4];
  const float* qkv_w = (const float*)d_in[5];
  const float* qkv_b = (const float*)d_in[6];
  const float* qkv_A = (const float*)d_in[7];
  const float* qkv_B = (const float*)d_in[8];
  const float* ao_w  = (const float*)d_in[9];
  const float* ao_b  = (const float*)d_in[10];
  const float* ao_A  = (const float*)d_in[11];
  const float* ao_B  = (const float*)d_in[12];
  const float* ln2_g = (const float*)d_in[13];
  const float* ln2_b = (const float*)d_in[14];
  const float* fc_w  = (const float*)d_in[15];
  const float* fc_b  = (const float*)d_in[16];
  const float* fc_A  = (const float*)d_in[17];
  const float* fc_B  = (const float*)d_in[18];
  const float* mo_w  = (const float*)d_in[19];
  const float* mo_b  = (const float*)d_in[20];
  const float* mo_A  = (const float*)d_in[21];
  const float* mo_B  = (const float*)d_in[22];
  const float* lnf_g = (const float*)d_in[23];
  const float* lnf_b = (const float*)d_in[24];
  float* out = (float*)d_out;

  float* ws = (float*)d_ws;
  const size_t MD = (size_t)M_ROWS * D_MODEL;
  float* h    = ws;
  float* x    = h   + MD;
  float* qkv  = x   + MD;
  float* att  = qkv + 3*MD;
  float* y    = att + MD;
  float* xa   = y   + 4*MD;
  unsigned* wabs   = (unsigned*)(xa + (size_t)M_ROWS*R_LORA);
  unsigned* kvkeys = wabs + 64;

  init_scratch<<<1, 64, 0, stream>>>(wabs, kvkeys);
  embed_kernel<<<M_ROWS, 256, 0, stream>>>(ids, wte, wpe, h);
  wabs_reduce<<<dim3(128, 48), 256, 0, stream>>>(qkv_w, ao_w, fc_w, mo_w, wabs);

  for (int l=0; l<N_LAYERS; l++){
    ln_kernel<<<M_ROWS, 256, 0, stream>>>(h, x, ln1_g + l*D_MODEL, ln1_b + l*D_MODEL);
    lora_xa_kernel<<<M_ROWS/16, 256, 0, stream>>>(x, qkv_A + (size_t)l*D_MODEL*R_LORA, xa, D_MODEL);
    gemm_qlora<false,false><<<dim3(M_ROWS/64, 3*D_MODEL/64), 256, 0, stream>>>(
        x, qkv_w + (size_t)l*D_MODEL*3*D_MODEL, wabs + l*4 + 0,
        qkv_b + (size_t)l*3*D_MODEL, xa, qkv_B + (size_t)l*R_LORA*3*D_MODEL,
        nullptr, qkv, 3*D_MODEL, D_MODEL);
    kv_minmax<<<256, 256, 0, stream>>>(qkv, kvkeys + l*4);
    kv_apply <<<256, 256, 0, stream>>>(qkv, kvkeys + l*4);
    attention_kernel<<<dim3(T_SEQ/64, BATCH*N_HEAD), 64, 0, stream>>>(qkv, att);
    lora_xa_kernel<<<M_ROWS/16, 256, 0, stream>>>(att, ao_A + (size_t)l*D_MODEL*R_LORA, xa, D_MODEL);
    gemm_qlora<true,false><<<dim3(M_ROWS/64, D_MODEL/64), 256, 0, stream>>>(
        att, ao_w + (size_t)l*D_MODEL*D_MODEL, wabs + l*4 + 1,
        ao_b + (size_t)l*D_MODEL, xa, ao_B + (size_t)l*R_LORA*D_MODEL,
        h, h, D_MODEL, D_MODEL);
    ln_kernel<<<M_ROWS, 256, 0, stream>>>(h, x, ln2_g + l*D_MODEL, ln2_b + l*D_MODEL);
    lora_xa_kernel<<<M_ROWS/16, 256, 0, stream>>>(x, fc_A + (size_t)l*D_MODEL*R_LORA, xa, D_MODEL);
    gemm_qlora<false,true><<<dim3(M_ROWS/64, 4*D_MODEL/64), 256, 0, stream>>>(
        x, fc_w + (size_t)l*D_MODEL*4*D_MODEL, wabs + l*4 + 2,
        fc_b + (size_t)l*4*D_MODEL, xa, fc_B + (size_t)l*R_LORA*4*D_MODEL,
        nullptr, y, 4*D_MODEL, D_MODEL);
    lora_xa_kernel<<<M_ROWS/16, 256, 0, stream>>>(y, mo_A + (size_t)l*4*D_MODEL*R_LORA, xa, 4*D_MODEL);
    gemm_qlora<true,false><<<dim3(M_ROWS/64, D_MODEL/64), 256, 0, stream>>>(
        y, mo_w + (size_t)l*4*D_MODEL*D_MODEL, wabs + l*4 + 3,
        mo_b + (size_t)l*D_MODEL, xa, mo_B + (size_t)l*R_LORA*D_MODEL,
        h, h, D_MODEL, 4*D_MODEL);
  }
  ln_kernel<<<M_ROWS, 256, 0, stream>>>(h, x, lnf_g, lnf_b);
  gemm_lmhead<<<dim3(M_ROWS/64, (V_VOCAB+63)/64), 256, 0, stream>>>(x, wte, out);
}

// Round 2
// 11725.397 us; speedup vs baseline: 3.1788x; 3.1788x over previous
//
#include <hip/hip_runtime.h>
#include <math.h>

#define N_LAYERS 12
#define D_MODEL 768
#define N_HEAD 12
#define HD 64
#define T_SEQ 1024
#define BATCH 2
#define M_ROWS 2048
#define V_VOCAB 50257
#define LORA_SCALE 2.0f
#define LN_EPS 1e-5f

typedef __attribute__((ext_vector_type(8))) short bf16x8v;
typedef __attribute__((ext_vector_type(4))) float f32x4;
typedef __attribute__((ext_vector_type(4))) unsigned int uint4v;
typedef __attribute__((ext_vector_type(4))) unsigned short ushort4v;

// ---- bf16 helpers (RNE) ----
__device__ __forceinline__ unsigned short f2bf(float f){
  unsigned u = __float_as_uint(f);
  return (unsigned short)((u + 0x7fffu + ((u >> 16) & 1u)) >> 16);
}
__device__ __forceinline__ float bf2f(unsigned short h){
  return __uint_as_float(((unsigned)h) << 16);
}

// ---- ordered-uint float key helpers ----
__device__ __forceinline__ unsigned fkey(float f){
  unsigned u = __float_as_uint(f);
  return (u & 0x80000000u) ? ~u : (u | 0x80000000u);
}
__device__ __forceinline__ float funkey(unsigned k){
  unsigned u = (k & 0x80000000u) ? (k & 0x7fffffffu) : ~k;
  return __uint_as_float(u);
}

// ---------- scratch init ----------
__global__ void init_scratch(unsigned* wabs, unsigned* kvkeys){
  int i = threadIdx.x;
  if (i < 48){
    wabs[i] = 0u;
    int t = i & 3;
    kvkeys[i] = (t==0 || t==2) ? 0xFFFFFFFFu : 0u;
  }
}

// ---------- embedding ----------
__global__ __launch_bounds__(256) void embed_kernel(const int* __restrict__ ids,
    const float* __restrict__ wte, const float* __restrict__ wpe, float* __restrict__ h){
  int m = blockIdx.x;
  int t = m & (T_SEQ-1);
  int id = ids[m];
  const float* wr = wte + (size_t)id * D_MODEL;
  const float* pr = wpe + (size_t)t  * D_MODEL;
  float* hr = h + (size_t)m * D_MODEL;
  #pragma unroll
  for (int i=0;i<3;i++){ int d = threadIdx.x + i*256; hr[d] = wr[d] + pr[d]; }
}

// ---------- per-tensor weight absmax (48 tensors) ----------
__global__ __launch_bounds__(256) void wabs_reduce(const float* __restrict__ qkv_w,
    const float* __restrict__ ao_w, const float* __restrict__ fc_w,
    const float* __restrict__ mo_w, unsigned* wabs){
  int t = blockIdx.y; int layer = t >> 2; int ty = t & 3;
  const float* base; size_t n;
  if (ty==0){ base = qkv_w + (size_t)layer*D_MODEL*3*D_MODEL; n = (size_t)D_MODEL*3*D_MODEL; }
  else if (ty==1){ base = ao_w + (size_t)layer*D_MODEL*D_MODEL; n = (size_t)D_MODEL*D_MODEL; }
  else if (ty==2){ base = fc_w + (size_t)layer*D_MODEL*4*D_MODEL; n = (size_t)D_MODEL*4*D_MODEL; }
  else { base = mo_w + (size_t)layer*4*D_MODEL*D_MODEL; n = (size_t)4*D_MODEL*D_MODEL; }
  float mx = 0.0f;
  for (size_t i = (size_t)blockIdx.x*256 + threadIdx.x; i < n; i += (size_t)gridDim.x*256)
    mx = fmaxf(mx, fabsf(base[i]));
  for (int o=32;o>0;o>>=1) mx = fmaxf(mx, __shfl_down(mx, o));
  if ((threadIdx.x & 63) == 0) atomicMax((int*)&wabs[t], __float_as_int(mx));
}

// ---------- weight prep: fakequant + transpose + bf16 hi/lo split ----------
// W [K][N] fp32 -> Whi/Wlo [N][K] bf16 (per layer)
__global__ __launch_bounds__(256) void prep_w(const float* __restrict__ W,
    unsigned short* __restrict__ Whi, unsigned short* __restrict__ Wlo,
    const unsigned* __restrict__ wabs, int K, int N, int type){
  int l = blockIdx.z;
  const float* Wb = W + (size_t)l*K*N;
  unsigned short* Hh = Whi + (size_t)l*K*N;
  unsigned short* Hl = Wlo + (size_t)l*K*N;
  float s = fmaxf(__uint_as_float(wabs[l*4+type]) / 127.0f, 1e-8f);
  __shared__ float T[64][65];
  int n0 = blockIdx.x*64, k0 = blockIdx.y*64;
  int tid = threadIdx.x;
  int kin = tid >> 4, nin = (tid & 15)*4;
  #pragma unroll
  for (int it=0; it<4; it++){
    int kk = kin + it*16;
    float4 wv = *reinterpret_cast<const float4*>(&Wb[(size_t)(k0+kk)*N + n0 + nin]);
    float q0 = fminf(fmaxf(rintf(wv.x / s), -128.f), 127.f) * s;
    float q1 = fminf(fmaxf(rintf(wv.y / s), -128.f), 127.f) * s;
    float q2 = fminf(fmaxf(rintf(wv.z / s), -128.f), 127.f) * s;
    float q3 = fminf(fmaxf(rintf(wv.w / s), -128.f), 127.f) * s;
    T[nin+0][kk] = q0; T[nin+1][kk] = q1; T[nin+2][kk] = q2; T[nin+3][kk] = q3;
  }
  __syncthreads();
  int nin2 = tid >> 4, kin2 = (tid & 15)*4;
  #pragma unroll
  for (int it=0; it<4; it++){
    int nn = nin2 + it*16;
    ushort4v hv, lv;
    #pragma unroll
    for (int e=0;e<4;e++){
      float w = T[nn][kin2+e];
      unsigned short h = f2bf(w);
      hv[e] = h; lv[e] = f2bf(w - bf2f(h));
    }
    size_t go = (size_t)(n0+nn)*K + k0 + kin2;
    *reinterpret_cast<ushort4v*>(&Hh[go]) = hv;
    *reinterpret_cast<ushort4v*>(&Hl[go]) = lv;
  }
}

// ---------- LoRA-B prep: Bl [16][N] fp32 -> blp [N][32] bf16 = [2*Bl | 2*Bl] ----------
__global__ __launch_bounds__(256) void prep_bl(const float* __restrict__ qkvB,
    const float* __restrict__ aoB, const float* __restrict__ fcB, const float* __restrict__ moB,
    unsigned short* __restrict__ dq, unsigned short* __restrict__ da,
    unsigned short* __restrict__ df, unsigned short* __restrict__ dm){
  int z = blockIdx.y; int l = z >> 2, t = z & 3;
  int N; const float* src; unsigned short* dst;
  if (t==0){ N = 3*D_MODEL; src = qkvB + (size_t)l*16*N; dst = dq + (size_t)l*N*32; }
  else if (t==1){ N = D_MODEL; src = aoB + (size_t)l*16*N; dst = da + (size_t)l*N*32; }
  else if (t==2){ N = 4*D_MODEL; src = fcB + (size_t)l*16*N; dst = df + (size_t)l*N*32; }
  else { N = D_MODEL; src = moB + (size_t)l*16*N; dst = dm + (size_t)l*N*32; }
  int idx = blockIdx.x*256 + threadIdx.x;
  if (idx >= N*16) return;
  int n = idx >> 4, r = idx & 15;
  unsigned short v = f2bf(2.0f * src[(size_t)r*N + n]);
  dst[(size_t)n*32 + r] = v;
  dst[(size_t)n*32 + 16 + r] = v;
}

// ---------- layernorm: 4 rows/block (1 wave each), writes fp32 + bf16 hi/lo planes ----------
__global__ __launch_bounds__(256) void ln_kernel(const float* __restrict__ in,
    float* __restrict__ xout, unsigned short* __restrict__ xhi, unsigned short* __restrict__ xlo,
    const float* __restrict__ g, const float* __restrict__ b){
  int w = threadIdx.x >> 6, lane = threadIdx.x & 63;
  int m = blockIdx.x*4 + w;
  const float* row = in + (size_t)m*D_MODEL;
  float xv[12];
  #pragma unroll
  for (int i=0;i<12;i++) xv[i] = row[lane + i*64];
  float s = 0.f;
  #pragma unroll
  for (int i=0;i<12;i++) s += xv[i];
  for (int o=32;o>0;o>>=1) s += __shfl_down(s, o);
  float mean = __shfl(s, 0) * (1.0f/768.0f);
  float sq = 0.f;
  #pragma unroll
  for (int i=0;i<12;i++){ float d = xv[i]-mean; sq += d*d; }
  for (int o=32;o>0;o>>=1) sq += __shfl_down(sq, o);
  float var = __shfl(sq, 0) * (1.0f/768.0f);
  float inv = 1.0f / sqrtf(var + LN_EPS);
  size_t base = (size_t)m*D_MODEL;
  #pragma unroll
  for (int i=0;i<12;i++){
    int d = lane + i*64;
    float v = (xv[i]-mean)*inv*g[d] + b[d];
    xout[base+d] = v;
    unsigned short h = f2bf(v);
    xhi[base+d] = h; xlo[base+d] = f2bf(v - bf2f(h));
  }
}

// ---------- lora xa = X @ A, output packed [M][32] bf16 = [hi(xa) | lo(xa)] ----------
__global__ __launch_bounds__(256) void lora_xa_kernel(const float* __restrict__ X,
    const float* __restrict__ A, unsigned short* __restrict__ xahl, int K){
  int t = threadIdx.x;
  int r = t & 15, kq = (t >> 4) & 7, rw = t >> 7;
  int m = blockIdx.x*2 + rw;
  int klen = K >> 3;
  const float* xr = X + (size_t)m*K + kq*klen;
  const float* ap = A + (size_t)(kq*klen)*16 + r;
  float acc = 0.f;
  for (int k=0; k<klen; k+=4){
    float4 xv = *reinterpret_cast<const float4*>(&xr[k]);
    acc += xv.x*ap[(k  )*16] + xv.y*ap[(k+1)*16] + xv.z*ap[(k+2)*16] + xv.w*ap[(k+3)*16];
  }
  __shared__ float red[2][8][16];
  red[rw][kq][r] = acc;
  __syncthreads();
  if (t < 32){
    int rw2 = t >> 4, r2 = t & 15;
    float sum = 0.f;
    #pragma unroll
    for (int c=0;c<8;c++) sum += red[rw2][c][r2];
    int mm = blockIdx.x*2 + rw2;
    unsigned short h = f2bf(sum);
    xahl[(size_t)mm*32 + r2] = h;
    xahl[(size_t)mm*32 + 16 + r2] = f2bf(sum - bf2f(h));
  }
}

// ---------- bf16x3 MFMA GEMM ----------
// A planes [M][K] bf16 hi/lo; B planes [N][K] bf16 hi/lo (or fp32 [N][K] if BFP32).
// If EPI>=1: one extra K=32 step with A=xahl [M][32], B=blp [N][32] (LoRA fold).
// EPI: 0 none; 1 bias; 2 bias+resid; 3 bias+gelu.
template<int MFRAG, int NFRAG, int EPI, bool BFP32, bool KVMM, bool PLANES>
__global__ __launch_bounds__(256) void gemm_x3(
    const unsigned short* __restrict__ Ahi, const unsigned short* __restrict__ Alo,
    const unsigned short* __restrict__ Bhi, const unsigned short* __restrict__ Blo,
    const float* __restrict__ Bf32,
    const unsigned short* __restrict__ xahl, const unsigned short* __restrict__ blp,
    const float* __restrict__ bias, const float* __restrict__ resid,
    float* __restrict__ out, unsigned short* __restrict__ ohi, unsigned short* __restrict__ olo,
    unsigned* kvdst, int N, int K)
{
  constexpr int BM = MFRAG*32;
  constexpr int BN = NFRAG*32;
  __shared__ unsigned short Ah[4][BM][8], Al[4][BM][8], Bh[4][BN][8], Bl_[4][BN][8];
  int m0 = blockIdx.x*BM, n0 = blockIdx.y*BN;
  int tid = threadIdx.x;
  int lane = tid & 63, wid = tid >> 6;
  int wm = wid >> 1, wn = wid & 1;
  int fr = lane & 15, kg = lane >> 4;

  f32x4 acc[MFRAG][NFRAG];
  #pragma unroll
  for (int i=0;i<MFRAG;i++)
    #pragma unroll
    for (int j=0;j<NFRAG;j++) acc[i][j] = (f32x4)(0.0f);

  int srow = tid >> 2, sc = tid & 3;
  const int KT = K + ((EPI>=1) ? 32 : 0);
  const uint4v zv = (uint4v)(0u);

  for (int k0 = 0; k0 < KT; k0 += 32){
    bool lstep = (EPI>=1) && (k0 >= K);
    // ---- stage A ----
    for (int r = srow; r < BM; r += 64){
      if (!lstep){
        size_t go = (size_t)(m0 + r)*K + k0 + sc*8;
        *reinterpret_cast<uint4v*>(&Ah[sc][r][0]) = *reinterpret_cast<const uint4v*>(&Ahi[go]);
        *reinterpret_cast<uint4v*>(&Al[sc][r][0]) = *reinterpret_cast<const uint4v*>(&Alo[go]);
      } else {
        size_t go = (size_t)(m0 + r)*32 + sc*8;
        *reinterpret_cast<uint4v*>(&Ah[sc][r][0]) = *reinterpret_cast<const uint4v*>(&xahl[go]);
        *reinterpret_cast<uint4v*>(&Al[sc][r][0]) = zv;
      }
    }
    // ---- stage B ----
    for (int r = srow; r < BN; r += 64){
      int col = n0 + r;
      if (!lstep){
        if constexpr (BFP32){
          union { unsigned short h[8]; uint4v v; } Uh;
          union { unsigned short h[8]; uint4v v; } Ul;
          if (col < N){
            const float* bp = &Bf32[(size_t)col*K + k0 + sc*8];
            #pragma unroll
            for (int e=0;e<8;e++){
              float w = bp[e];
              unsigned short h = f2bf(w);
              Uh.h[e] = h; Ul.h[e] = f2bf(w - bf2f(h));
            }
          } else { Uh.v = zv; Ul.v = zv; }
          *reinterpret_cast<uint4v*>(&Bh[sc][r][0]) = Uh.v;
          *reinterpret_cast<uint4v*>(&Bl_[sc][r][0]) = Ul.v;
        } else {
          size_t go = (size_t)col*K + k0 + sc*8;
          *reinterpret_cast<uint4v*>(&Bh[sc][r][0]) = *reinterpret_cast<const uint4v*>(&Bhi[go]);
          *reinterpret_cast<uint4v*>(&Bl_[sc][r][0]) = *reinterpret_cast<const uint4v*>(&Blo[go]);
        }
      } else {
        size_t go = (size_t)col*32 + sc*8;
        *reinterpret_cast<uint4v*>(&Bh[sc][r][0]) = *reinterpret_cast<const uint4v*>(&blp[go]);
        *reinterpret_cast<uint4v*>(&Bl_[sc][r][0]) = zv;
      }
    }
    __syncthreads();
    bf16x8v af[MFRAG], alf[MFRAG], bf_[NFRAG], blf[NFRAG];
    #pragma unroll
    for (int i=0;i<MFRAG;i++){
      int ar = wm*(BM/2) + i*16 + fr;
      af[i]  = *reinterpret_cast<const bf16x8v*>(&Ah[kg][ar][0]);
      alf[i] = *reinterpret_cast<const bf16x8v*>(&Al[kg][ar][0]);
    }
    #pragma unroll
    for (int j=0;j<NFRAG;j++){
      int br = wn*(BN/2) + j*16 + fr;
      bf_[j] = *reinterpret_cast<const bf16x8v*>(&Bh[kg][br][0]);
      blf[j] = *reinterpret_cast<const bf16x8v*>(&Bl_[kg][br][0]);
    }
    #pragma unroll
    for (int i=0;i<MFRAG;i++)
      #pragma unroll
      for (int j=0;j<NFRAG;j++){
        acc[i][j] = __builtin_amdgcn_mfma_f32_16x16x32_bf16(af[i],  bf_[j], acc[i][j], 0, 0, 0);
        acc[i][j] = __builtin_amdgcn_mfma_f32_16x16x32_bf16(af[i],  blf[j], acc[i][j], 0, 0, 0);
        acc[i][j] = __builtin_amdgcn_mfma_f32_16x16x32_bf16(alf[i], bf_[j], acc[i][j], 0, 0, 0);
      }
    __syncthreads();
  }

  // ---- epilogue ----
  float kmn = 1e30f, kmx = -1e30f;
  int q4 = lane >> 4;
  #pragma unroll
  for (int j=0;j<NFRAG;j++){
    int n = n0 + wn*(BN/2) + j*16 + fr;
    float bn = 0.f;
    if constexpr (EPI>=1) bn = bias[n];
    #pragma unroll
    for (int i=0;i<MFRAG;i++){
      #pragma unroll
      for (int q=0;q<4;q++){
        int m = m0 + wm*(BM/2) + i*16 + q4*4 + q;
        float v = acc[i][j][q] + bn;
        if constexpr (EPI==2) v += resid[(size_t)m*N + n];
        if constexpr (EPI==3) v = 0.5f*v*(1.0f + erff(v*0.70710678118654752f));
        bool ok = true;
        if constexpr (BFP32) ok = (n < N);
        if (ok){
          out[(size_t)m*N + n] = v;
          if constexpr (PLANES){
            unsigned short h = f2bf(v);
            ohi[(size_t)m*N + n] = h;
            olo[(size_t)m*N + n] = f2bf(v - bf2f(h));
          }
        }
        if constexpr (KVMM){ kmn = fminf(kmn, v); kmx = fmaxf(kmx, v); }
      }
    }
  }
  if constexpr (KVMM){
    if (n0 >= D_MODEL){
      for (int o=32;o>0;o>>=1){
        kmn = fminf(kmn, __shfl_down(kmn, o));
        kmx = fmaxf(kmx, __shfl_down(kmx, o));
      }
      if (lane == 0){
        int slot = (n0 >= 2*D_MODEL) ? 2 : 0;
        atomicMin(&kvdst[slot],   fkey(kmn));
        atomicMax(&kvdst[slot+1], fkey(kmx));
      }
    }
  }
}

// ---------- apply asymmetric fake-quant to k and v in place ----------
__global__ __launch_bounds__(256) void kv_apply(float* qkv, const unsigned* __restrict__ keys){
  float kmn = funkey(keys[0]), kmx = funkey(keys[1]);
  float vmn = funkey(keys[2]), vmx = funkey(keys[3]);
  float ks = fmaxf((kmx - kmn) / 255.0f, 1e-8f);
  float kz = rintf(-kmn / ks);
  float vs = fmaxf((vmx - vmn) / 255.0f, 1e-8f);
  float vz = rintf(-vmn / vs);
  int m = blockIdx.x;
  float* rowk = qkv + (size_t)m*(3*D_MODEL) + D_MODEL;
  float* rowv = rowk + D_MODEL;
  #pragma unroll
  for (int i=0;i<3;i++){
    int c = threadIdx.x + i*256;
    float xk = rowk[c];
    rowk[c] = (fminf(fmaxf(rintf(xk/ks) + kz, 0.0f), 255.0f) - kz) * ks;
    float xv = rowv[c];
    rowv[c] = (fminf(fmaxf(rintf(xv/vs) + vz, 0.0f), 255.0f) - vz) * vs;
  }
}

// ---------- attention: split-k partials (1 wave / 64 q-rows / 256-k chunk) ----------
__global__ __launch_bounds__(64) void attn_partial(const float* __restrict__ qkv,
    float* __restrict__ po, float* __restrict__ pml){
  int qt = blockIdx.x, bh = blockIdx.y, kc = blockIdx.z;
  if (kc*256 >= (qt+1)*64) return;
  int b = bh / N_HEAD, hh = bh % N_HEAD;
  int tid = threadIdx.x;
  int qi = qt*64 + tid;
  const float* base = qkv + (size_t)b * T_SEQ * (3*D_MODEL);
  float q[HD];
  #pragma unroll
  for (int d=0; d<HD; d++) q[d] = base[(size_t)qi*(3*D_MODEL) + hh*HD + d];
  float o[HD];
  #pragma unroll
  for (int d=0; d<HD; d++) o[d] = 0.0f;
  float mrun = -1e30f, lrun = 0.0f;
  __shared__ float Ks[64][HD];
  __shared__ float Vs[64][HD];
  for (int st=0; st<4; st++){
    int kb = kc*256 + st*64;
    if (kb >= (qt+1)*64) break;
    for (int r=0;r<64;r++){
      Ks[r][tid] = base[(size_t)(kb+r)*(3*D_MODEL) + D_MODEL   + hh*HD + tid];
      Vs[r][tid] = base[(size_t)(kb+r)*(3*D_MODEL) + 2*D_MODEL + hh*HD + tid];
    }
    __syncthreads();
    int kmax = min(64, qi - kb + 1);
    for (int kk=0; kk<kmax; kk++){
      float s0=0.f,s1=0.f,s2=0.f,s3=0.f;
      #pragma unroll
      for (int d=0; d<HD; d+=4){
        s0 += q[d  ]*Ks[kk][d  ];
        s1 += q[d+1]*Ks[kk][d+1];
        s2 += q[d+2]*Ks[kk][d+2];
        s3 += q[d+3]*Ks[kk][d+3];
      }
      float s = ((s0+s1)+(s2+s3)) * 0.125f;
      float nm = fmaxf(mrun, s);
      float sc = expf(mrun - nm);
      float p  = expf(s - nm);
      lrun = lrun*sc + p;
      #pragma unroll
      for (int d=0; d<HD; d++) o[d] = o[d]*sc + p*Vs[kk][d];
      mrun = nm;
    }
    __syncthreads();
  }
  size_t idx = ((size_t)kc*24 + bh)*T_SEQ + qi;
  float* pr = po + idx*HD;
  #pragma unroll
  for (int d=0; d<HD; d++) pr[d] = o[d];
  pml[idx*2]   = mrun;
  pml[idx*2+1] = lrun;
}

// ---------- attention combine -> att fp32 + bf16 planes ----------
__global__ __launch_bounds__(256) void attn_combine(const float* __restrict__ po,
    const float* __restrict__ pml, float* __restrict__ att,
    unsigned short* __restrict__ ahi, unsigned short* __restrict__ alo){
  int qt = blockIdx.x, bh = blockIdx.y;
  int b = bh / N_HEAD, hh = bh % N_HEAD;
  int d = threadIdx.x & 63, rr = threadIdx.x >> 6;
  for (int r0=0; r0<64; r0+=4){
    int qi = qt*64 + r0 + rr;
    int nch = qi/256 + 1;
    float mv[4], lv[4];
    float M = -1e30f;
    for (int c=0;c<nch;c++){
      size_t idx = ((size_t)c*24 + bh)*T_SEQ + qi;
      mv[c] = pml[idx*2]; lv[c] = pml[idx*2+1];
      M = fmaxf(M, mv[c]);
    }
    float L = 0.f, ov = 0.f;
    for (int c=0;c<nch;c++){
      float e = expf(mv[c] - M);
      L += lv[c]*e;
      size_t idx = ((size_t)c*24 + bh)*T_SEQ + qi;
      ov += po[idx*HD + d]*e;
    }
    float a = ov / L;
    size_t oidx = (size_t)(b*T_SEQ + qi)*D_MODEL + hh*HD + d;
    att[oidx] = a;
    unsigned short h = f2bf(a);
    ahi[oidx] = h; alo[oidx] = f2bf(a - bf2f(h));
  }
}

extern "C" void kernel_launch(void* const* d_in, const int* in_sizes, int n_in,
                              void* d_out, int out_size, void* d_ws, size_t ws_size,
                              hipStream_t stream){
  const int*   ids   = (const int*)  d_in[0];
  const float* wte   = (const float*)d_in[1];
  const float* wpe   = (const float*)d_in[2];
  const float* ln1_g = (const float*)d_in[3];
  const float* ln1_b = (const float*)d_in[4];
  const float* qkv_w = (const float*)d_in[5];
  const float* qkv_b = (const float*)d_in[6];
  const float* qkv_A = (const float*)d_in[7];
  const float* qkv_B = (const float*)d_in[8];
  const float* ao_w  = (const float*)d_in[9];
  const float* ao_b  = (const float*)d_in[10];
  const float* ao_A  = (const float*)d_in[11];
  const float* ao_B  = (const float*)d_in[12];
  const float* ln2_g = (const float*)d_in[13];
  const float* ln2_b = (const float*)d_in[14];
  const float* fc_w  = (const float*)d_in[15];
  const float* fc_b  = (const float*)d_in[16];
  const float* fc_A  = (const float*)d_in[17];
  const float* fc_B  = (const float*)d_in[18];
  const float* mo_w  = (const float*)d_in[19];
  const float* mo_b  = (const float*)d_in[20];
  const float* mo_A  = (const float*)d_in[21];
  const float* mo_B  = (const float*)d_in[22];
  const float* lnf_g = (const float*)d_in[23];
  const float* lnf_b = (const float*)d_in[24];
  float* out = (float*)d_out;

  char* p = (char*)d_ws;
  auto alloc = [&](size_t bytes)->char*{ char* r = p; p += (bytes + 255) & ~(size_t)255; return r; };
  const size_t MD = (size_t)M_ROWS * D_MODEL;

  float* h    = (float*)alloc(MD*4);
  float* x    = (float*)alloc(MD*4);
  float* qkv  = (float*)alloc(3*MD*4);
  float* att  = (float*)alloc(MD*4);
  float* y    = (float*)alloc(4*MD*4);
  float* po   = (float*)alloc((size_t)4*24*T_SEQ*HD*4);
  float* pml  = (float*)alloc((size_t)4*24*T_SEQ*2*4);
  unsigned short* xahl = (unsigned short*)alloc((size_t)M_ROWS*32*2);
  unsigned short* x_hi = (unsigned short*)alloc(MD*2);
  unsigned short* x_lo = (unsigned short*)alloc(MD*2);
  unsigned short* a_hi = (unsigned short*)alloc(MD*2);
  unsigned short* a_lo = (unsigned short*)alloc(MD*2);
  unsigned short* y_hi = (unsigned short*)alloc(4*MD*2);
  unsigned short* y_lo = (unsigned short*)alloc(4*MD*2);
  const size_t WQ = (size_t)N_LAYERS*D_MODEL*3*D_MODEL;
  const size_t WA = (size_t)N_LAYERS*D_MODEL*D_MODEL;
  const size_t WF = (size_t)N_LAYERS*D_MODEL*4*D_MODEL;
  unsigned short* Wq_hi = (unsigned short*)alloc(WQ*2);
  unsigned short* Wq_lo = (unsigned short*)alloc(WQ*2);
  unsigned short* Wa_hi = (unsigned short*)alloc(WA*2);
  unsigned short* Wa_lo = (unsigned short*)alloc(WA*2);
  unsigned short* Wf_hi = (unsigned short*)alloc(WF*2);
  unsigned short* Wf_lo = (unsigned short*)alloc(WF*2);
  unsigned short* Wm_hi = (unsigned short*)alloc(WF*2);
  unsigned short* Wm_lo = (unsigned short*)alloc(WF*2);
  unsigned short* blp_q = (unsigned short*)alloc((size_t)N_LAYERS*3*D_MODEL*32*2);
  unsigned short* blp_a = (unsigned short*)alloc((size_t)N_LAYERS*D_MODEL*32*2);
  unsigned short* blp_f = (unsigned short*)alloc((size_t)N_LAYERS*4*D_MODEL*32*2);
  unsigned short* blp_m = (unsigned short*)alloc((size_t)N_LAYERS*D_MODEL*32*2);
  unsigned* wabs   = (unsigned*)alloc(64*4);
  unsigned* kvkeys = (unsigned*)alloc(64*4);

  init_scratch<<<1, 64, 0, stream>>>(wabs, kvkeys);
  embed_kernel<<<M_ROWS, 256, 0, stream>>>(ids, wte, wpe, h);
  wabs_reduce<<<dim3(128, 48), 256, 0, stream>>>(qkv_w, ao_w, fc_w, mo_w, wabs);
  prep_w<<<dim3(36, 12, 12), 256, 0, stream>>>(qkv_w, Wq_hi, Wq_lo, wabs, D_MODEL, 3*D_MODEL, 0);
  prep_w<<<dim3(12, 12, 12), 256, 0, stream>>>(ao_w,  Wa_hi, Wa_lo, wabs, D_MODEL, D_MODEL,   1);
  prep_w<<<dim3(48, 12, 12), 256, 0, stream>>>(fc_w,  Wf_hi, Wf_lo, wabs, D_MODEL, 4*D_MODEL, 2);
  prep_w<<<dim3(12, 48, 12), 256, 0, stream>>>(mo_w,  Wm_hi, Wm_lo, wabs, 4*D_MODEL, D_MODEL, 3);
  prep_bl<<<dim3(192, 48), 256, 0, stream>>>(qkv_B, ao_B, fc_B, mo_B, blp_q, blp_a, blp_f, blp_m);

  for (int l=0; l<N_LAYERS; l++){
    ln_kernel<<<M_ROWS/4, 256, 0, stream>>>(h, x, x_hi, x_lo, ln1_g + l*D_MODEL, ln1_b + l*D_MODEL);
    lora_xa_kernel<<<M_ROWS/2, 256, 0, stream>>>(x, qkv_A + (size_t)l*D_MODEL*16, xahl, D_MODEL);
    gemm_x3<4,4,1,false,true,false><<<dim3(16, 18), 256, 0, stream>>>(
        x_hi, x_lo, Wq_hi + (size_t)l*D_MODEL*3*D_MODEL, Wq_lo + (size_t)l*D_MODEL*3*D_MODEL, nullptr,
        xahl, blp_q + (size_t)l*3*D_MODEL*32, qkv_b + (size_t)l*3*D_MODEL, nullptr,
        qkv, nullptr, nullptr, kvkeys + l*4, 3*D_MODEL, D_MODEL);
    kv_apply<<<M_ROWS, 256, 0, stream>>>(qkv, kvkeys + l*4);
    attn_partial<<<dim3(T_SEQ/64, BATCH*N_HEAD, 4), 64, 0, stream>>>(qkv, po, pml);
    attn_combine<<<dim3(T_SEQ/64, BATCH*N_HEAD), 256, 0, stream>>>(po, pml, att, a_hi, a_lo);
    lora_xa_kernel<<<M_ROWS/2, 256, 0, stream>>>(att, ao_A + (size_t)l*D_MODEL*16, xahl, D_MODEL);
    gemm_x3<2,2,2,false,false,false><<<dim3(32, 12), 256, 0, stream>>>(
        a_hi, a_lo, Wa_hi + (size_t)l*D_MODEL*D_MODEL, Wa_lo + (size_t)l*D_MODEL*D_MODEL, nullptr,
        xahl, blp_a + (size_t)l*D_MODEL*32, ao_b + (size_t)l*D_MODEL, h,
        h, nullptr, nullptr, nullptr, D_MODEL, D_MODEL);
    ln_kernel<<<M_ROWS/4, 256, 0, stream>>>(h, x, x_hi, x_lo, ln2_g + l*D_MODEL, ln2_b + l*D_MODEL);
    lora_xa_kernel<<<M_ROWS/2, 256, 0, stream>>>(x, fc_A + (size_t)l*D_MODEL*16, xahl, D_MODEL);
    gemm_x3<4,4,3,false,false,true><<<dim3(16, 24), 256, 0, stream>>>(
        x_hi, x_lo, Wf_hi + (size_t)l*D_MODEL*4*D_MODEL, Wf_lo + (size_t)l*D_MODEL*4*D_MODEL, nullptr,
        xahl, blp_f + (size_t)l*4*D_MODEL*32, fc_b + (size_t)l*4*D_MODEL, nullptr,
        y, y_hi, y_lo, nullptr, 4*D_MODEL, D_MODEL);
    lora_xa_kernel<<<M_ROWS/2, 256, 0, stream>>>(y, mo_A + (size_t)l*4*D_MODEL*16, xahl, 4*D_MODEL);
    gemm_x3<2,2,2,false,false,false><<<dim3(32, 12), 256, 0, stream>>>(
        y_hi, y_lo, Wm_hi + (size_t)l*4*D_MODEL*D_MODEL, Wm_lo + (size_t)l*4*D_MODEL*D_MODEL, nullptr,
        xahl, blp_m + (size_t)l*D_MODEL*32, mo_b + (size_t)l*D_MODEL, h,
        h, nullptr, nullptr, nullptr, D_MODEL, 4*D_MODEL);
  }
  ln_kernel<<<M_ROWS/4, 256, 0, stream>>>(h, x, x_hi, x_lo, lnf_g, lnf_b);
  gemm_x3<4,4,0,true,false,false><<<dim3(16, 393), 256, 0, stream>>>(
      x_hi, x_lo, nullptr, nullptr, wte,
      nullptr, nullptr, nullptr, nullptr,
      out, nullptr, nullptr, nullptr, V_VOCAB, D_MODEL);
}